// Round 12
// baseline (37.337 us; speedup 1.0000x reference)
//
#include <hip/hip_runtime.h>
#include <math.h>

#define NLEAVES 8192
constexpr int NT    = 512;          // threads/block (8 waves)
constexpr int NSLOT = 16;           // 32-lane q-slots

typedef float f32x2 __attribute__((ext_vector_type(2)));

#if __has_builtin(__builtin_elementwise_fma)
#define PKFMA(B, E, U) (U) = __builtin_elementwise_fma((B), (E), (U))
#else
#define PKFMA(B, E, U) do { (U).x = fmaf((B).x, (E).x, (U).x); \
                            (U).y = fmaf((B).y, (E).y, (U).y); } while (0)
#endif

// ---- LDS layout (floats) ----
// E bf16-packed: Eu4[(l*4 + r8)*32 + lp] = uint4 of 8 bf16 = exp(T[lp][l][8*r8..+7])
constexpr int ROWP  = 36;                       // 144B rows, 16B-aligned
constexpr int PARTP = 33;
constexpr int OFF_E    = 0;
constexpr int OFF_BUF  = 16384;                 // E: 64 KB bf16
constexpr int OFF_P0   = OFF_BUF + 32 * ROWP;
constexpr int OFF_P1   = OFF_P0 + NSLOT * PARTP;
constexpr int OFF_P2   = OFF_P1 + NSLOT * PARTP;
constexpr int OFF_P3   = OFF_P2 + NSLOT * PARTP;
constexpr int OFF_R    = OFF_P3 + NSLOT * PARTP;
constexpr int OFF_FLAG = OFF_R + 64;
constexpr int SMEM_F32 = OFF_FLAG + 4;
constexpr size_t SMEM_BYTES = (size_t)SMEM_F32 * 4;   // ~79 KB

// bf16 pair pack (RNE) / unpack via bit ops (1 VALU per value)
__device__ __forceinline__ unsigned bfpack(float lo, float hi) {
    unsigned a = __float_as_uint(lo), b = __float_as_uint(hi);
    a = (a + 0x7fffu + ((a >> 16) & 1u)) >> 16;
    b = (b + 0x7fffu + ((b >> 16) & 1u)) >> 16;
    return (b << 16) | a;
}
__device__ __forceinline__ f32x2 upk(unsigned u) {
    f32x2 r;
    r.x = __uint_as_float(u << 16);
    r.y = __uint_as_float(u & 0xffff0000u);
    return r;
}

// Build bf16 exp(T) into LDS. lp-fastest decomposition -> each half-wave
// writes a contiguous swizzle-free 512B block (conflict-free b128 writes).
__device__ __forceinline__ void build_E(const float* __restrict__ trans,
                                        float* sm, int tid, int bid) {
    const float4* t4 = (const float4*)trans;    // t4[lp*256 + l*8 + r8*2]
    uint4* E4 = (uint4*)(sm + OFF_E);
    #pragma unroll
    for (int it = 0; it < 8; ++it) {
        const int i = (tid + it * NT + bid * 32) & 4095;  // block-rotated
        const int lp = i & 31, rem = i >> 5;              // rem = l*4 + r8
        float4 v0 = t4[lp * 256 + rem * 2];
        float4 v1 = t4[lp * 256 + rem * 2 + 1];
        uint4 u;
        u.x = bfpack(__expf(v0.x), __expf(v0.y));
        u.y = bfpack(__expf(v0.z), __expf(v0.w));
        u.z = bfpack(__expf(v1.x), __expf(v1.y));
        u.w = bfpack(__expf(v1.z), __expf(v1.w));
        E4[rem * 32 + lp] = u;
    }
}

// Load pre-built bf16 E straight from ws (written by k1 block 0): 64 KB copy.
__device__ __forceinline__ void load_E(const float* __restrict__ wsE,
                                       float* sm, int tid) {
    const uint4* src = (const uint4*)wsE;
    uint4* E4 = (uint4*)(sm + OFF_E);
    #pragma unroll
    for (int it = 0; it < 8; ++it)
        E4[tid + it * NT] = src[tid + it * NT];
}

// Reduce IN consecutive score rows through LEVELS levels in LDS; root row ->
// outp[blk*32+lp]. NTOT = global node count at input level. m>=4: quad path
// (4 nodes per E read; half-waves share E addrs at m>=8 -> LDS broadcast).
template<int IN, int LEVELS>
__device__ __forceinline__
void subtree(const float* __restrict__ in, float* __restrict__ outp,
             const float* __restrict__ iem, int NTOT, int blk,
             float* sm, int tid, int lp, int q) {
    float* buf = sm + OFF_BUF;
    float* p0  = sm + OFF_P0;
    float* p1  = sm + OFF_P1;
    float* p2  = sm + OFF_P2;
    float* p3  = sm + OFF_P3;
    float* rm  = sm + OFF_R;
    const uint4* Eu = (const uint4*)(sm + OFF_E);

    // prepass: rows -> exp(v - rowmax); rowmax -> rm (parity 0)
    for (int rr = q; rr < IN; rr += NSLOT) {
        float v = in[(blk * IN + rr) * 32 + lp];
        float gm = v;
        #pragma unroll
        for (int kk = 16; kk >= 1; kk >>= 1) gm = fmaxf(gm, __shfl_xor(gm, kk));
        buf[rr * ROWP + lp] = __expf(v - gm);
        if (lp == 0) rm[rr] = gm;
    }
    __syncthreads();

    #pragma unroll
    for (int k = 1; k <= LEVELS; ++k) {
        const int m = IN >> k;                    // nodes this level
        const float* rprev = rm + ((k & 1) ? 0 : 32);
        float*       rnext = rm + ((k & 1) ? 32 : 0);
        int S_acc;                                // segments to sum in phase 2

        if (m >= 4) {
            // ---- quad phase 1: 4 nodes share each E read ----
            const int nq   = m >> 2;
            const int S    = NSLOT / nq;
            const int llen = 32 / S;
            const int lgnq = (nq == 4) ? 2 : (nq == 2) ? 1 : 0;
            const int quad = q & (nq - 1);
            const int seg  = q >> lgnq;
            const int base = 8 * quad;
            S_acc = S;

            float4 b0[8], b1[8], b2[8], b3[8];
            {
                const float4* pb0 = (const float4*)(buf + (base + 1) * ROWP);
                const float4* pb1 = (const float4*)(buf + (base + 3) * ROWP);
                const float4* pb2 = (const float4*)(buf + (base + 5) * ROWP);
                const float4* pb3 = (const float4*)(buf + (base + 7) * ROWP);
                #pragma unroll
                for (int r = 0; r < 8; ++r) {
                    b0[r] = pb0[r]; b1[r] = pb1[r];
                    b2[r] = pb2[r]; b3[r] = pb3[r];
                }
            }
            float s0 = 0.f, s1v = 0.f, s2v = 0.f, s3v = 0.f;
            #pragma unroll
            for (int li = 0; li < llen; ++li) {
                const int l = seg * llen + li;
                const float a0 = buf[(base + 0) * ROWP + l];
                const float a1 = buf[(base + 2) * ROWP + l];
                const float a2 = buf[(base + 4) * ROWP + l];
                const float a3 = buf[(base + 6) * ROWP + l];
                const uint4* Ep = Eu + l * 128 + lp;
                f32x2 u0 = {0.f, 0.f}, u1 = {0.f, 0.f};
                f32x2 u2 = {0.f, 0.f}, u3 = {0.f, 0.f};
                #pragma unroll
                for (int r8 = 0; r8 < 4; ++r8) {
                    const uint4 e = Ep[r8 * 32];          // 8 bf16 = r 8*r8..+7
                    const f32x2 e0 = upk(e.x), e1 = upk(e.y);
                    const f32x2 e2 = upk(e.z), e3 = upk(e.w);
                    const float4 c0 = b0[2 * r8], d0 = b0[2 * r8 + 1];
                    const float4 c1 = b1[2 * r8], d1 = b1[2 * r8 + 1];
                    const float4 c2 = b2[2 * r8], d2 = b2[2 * r8 + 1];
                    const float4 c3 = b3[2 * r8], d3 = b3[2 * r8 + 1];
                    PKFMA(((f32x2){c0.x, c0.y}), e0, u0);
                    PKFMA(((f32x2){c0.z, c0.w}), e1, u0);
                    PKFMA(((f32x2){d0.x, d0.y}), e2, u0);
                    PKFMA(((f32x2){d0.z, d0.w}), e3, u0);
                    PKFMA(((f32x2){c1.x, c1.y}), e0, u1);
                    PKFMA(((f32x2){c1.z, c1.w}), e1, u1);
                    PKFMA(((f32x2){d1.x, d1.y}), e2, u1);
                    PKFMA(((f32x2){d1.z, d1.w}), e3, u1);
                    PKFMA(((f32x2){c2.x, c2.y}), e0, u2);
                    PKFMA(((f32x2){c2.z, c2.w}), e1, u2);
                    PKFMA(((f32x2){d2.x, d2.y}), e2, u2);
                    PKFMA(((f32x2){d2.z, d2.w}), e3, u2);
                    PKFMA(((f32x2){c3.x, c3.y}), e0, u3);
                    PKFMA(((f32x2){c3.z, c3.w}), e1, u3);
                    PKFMA(((f32x2){d3.x, d3.y}), e2, u3);
                    PKFMA(((f32x2){d3.z, d3.w}), e3, u3);
                }
                s0  = fmaf(a0, u0.x + u0.y, s0);
                s1v = fmaf(a1, u1.x + u1.y, s1v);
                s2v = fmaf(a2, u2.x + u2.y, s2v);
                s3v = fmaf(a3, u3.x + u3.y, s3v);
            }
            p0[q * PARTP + lp] = s0;
            p1[q * PARTP + lp] = s1v;
            p2[q * PARTP + lp] = s2v;
            p3[q * PARTP + lp] = s3v;
        } else {
            // ---- pair phase 1 (m <= 2) ----
            const int llen = 2;                   // S = 16
            const int seg  = q;
            S_acc = 16;
            float4 b0[8], b1[8];
            {
                const float4* pb0 = (const float4*)(buf + 1 * ROWP);
                const float4* pb1 = (const float4*)(buf + 3 * ROWP);
                #pragma unroll
                for (int r = 0; r < 8; ++r) { b0[r] = pb0[r]; b1[r] = pb1[r]; }
            }
            float s0 = 0.f, s1v = 0.f;
            #pragma unroll
            for (int li = 0; li < llen; ++li) {
                const int l = seg * llen + li;
                const float a0 = buf[0 * ROWP + l];
                const float a1 = buf[2 * ROWP + l];
                const uint4* Ep = Eu + l * 128 + lp;
                f32x2 u0 = {0.f, 0.f}, u1 = {0.f, 0.f};
                #pragma unroll
                for (int r8 = 0; r8 < 4; ++r8) {
                    const uint4 e = Ep[r8 * 32];
                    const f32x2 e0 = upk(e.x), e1 = upk(e.y);
                    const f32x2 e2 = upk(e.z), e3 = upk(e.w);
                    const float4 c0 = b0[2 * r8], d0 = b0[2 * r8 + 1];
                    const float4 c1 = b1[2 * r8], d1 = b1[2 * r8 + 1];
                    PKFMA(((f32x2){c0.x, c0.y}), e0, u0);
                    PKFMA(((f32x2){c0.z, c0.w}), e1, u0);
                    PKFMA(((f32x2){d0.x, d0.y}), e2, u0);
                    PKFMA(((f32x2){d0.z, d0.w}), e3, u0);
                    PKFMA(((f32x2){c1.x, c1.y}), e0, u1);
                    PKFMA(((f32x2){c1.z, c1.w}), e1, u1);
                    PKFMA(((f32x2){d1.x, d1.y}), e2, u1);
                    PKFMA(((f32x2){d1.z, d1.w}), e3, u1);
                }
                s0  = fmaf(a0, u0.x + u0.y, s0);
                s1v = fmaf(a1, u1.x + u1.y, s1v);
            }
            p0[q * PARTP + lp] = s0;
            p1[q * PARTP + lp] = s1v;
        }
        __syncthreads();

        // ---- phase 2: combine partials, add emissions, log ----
        if (tid < m * 32) {
            const int node = q;
            float acc = 0.f;
            if (m >= 4) {
                const int nq = m >> 2;
                const int j  = node & 3;
                const int qd = node >> 2;
                const float* pp = (j == 0) ? p0 : (j == 1) ? p1 : (j == 2) ? p2 : p3;
                #pragma unroll
                for (int s = 0; s < 16; ++s) {
                    if (s < S_acc) acc += pp[(s * nq + qd) * PARTP + lp];
                }
            } else {
                const float* pp = (node & 1) ? p1 : p0;
                #pragma unroll
                for (int s = 0; s < 16; ++s) acc += pp[s * PARTP + lp];
            }
            const float em = iem[(NLEAVES - 2 * (NTOT >> k) + blk * m + node) * 32 + lp];
            const float raw = em + rprev[2 * node] + rprev[2 * node + 1] + __logf(acc);
            if (k == LEVELS) {
                outp[blk * 32 + lp] = raw;        // m==1, node==0
            } else {
                float gm = raw;
                #pragma unroll
                for (int kk = 16; kk >= 1; kk >>= 1) gm = fmaxf(gm, __shfl_xor(gm, kk));
                buf[node * ROWP + lp] = __expf(raw - gm);  // in-place: phase2 reads only p/rm
                if (lp == 0) rnext[node] = gm;
            }
        }
        __syncthreads();
    }
}

// K1: 256 blocks, 32 leaves each -> s1[256 rows]. Block 0 spills its finished
// bf16 exp(T) (64 KB) to wsE so the tail skips the expf rebuild. Kernel
// boundary = the system-level flush for s1/wsE (R6/R7: intra-kernel 256-block
// handoff is racy; R9: grid.sync costs ~37us each).
__global__ __launch_bounds__(NT, 1)
void k1_kernel(const float* __restrict__ leaf, float* __restrict__ s1,
               const float* __restrict__ iem, const float* __restrict__ trans,
               float* __restrict__ wsE) {
    extern __shared__ __align__(16) float sm[];
    const int tid = threadIdx.x, lp = tid & 31, q = tid >> 5;
    build_E(trans, sm, tid, blockIdx.x);
    if (blockIdx.x == 0) {
        __syncthreads();                          // E fully built before readback
        const uint4* E4 = (const uint4*)(sm + OFF_E);
        uint4* dst = (uint4*)wsE;
        #pragma unroll
        for (int it = 0; it < 8; ++it)
            dst[tid + it * NT] = E4[tid + it * NT];
    }
    subtree<32, 5>(leaf, s1, iem, 8192, blockIdx.x, sm, tid, lp, q);
}

// Tail: 16 blocks reduce s1(256 rows) -> s2(16 rows); the last arriver
// reduces s2(16) -> out. Persistent counter, never reset: among any 16
// consecutive fetch_add returns exactly one satisfies (old&15)==15
// (wrap-safe from the 0xAA poison) -> no memset node. Fences = R5/R8 verbatim.
__global__ __launch_bounds__(NT, 1)
void tail_kernel(const float* __restrict__ s1, float* __restrict__ s2,
                 float* __restrict__ out, const float* __restrict__ iem,
                 const float* __restrict__ wsE, unsigned* __restrict__ cnt) {
    extern __shared__ __align__(16) float sm[];
    const int tid = threadIdx.x, lp = tid & 31, q = tid >> 5;
    int* flag = (int*)(sm + OFF_FLAG);
    load_E(wsE, sm, tid);
    subtree<16, 4>(s1, s2, iem, 256, blockIdx.x, sm, tid, lp, q);

    if (tid == 0) {
        __threadfence();                              // release s2 row device-wide
        unsigned old = atomicAdd(cnt, 1u);
        *flag = ((old & 15u) == 15u) ? 1 : 0;
    }
    __syncthreads();
    if (!*flag) return;
    if (tid == 0) __threadfence();                    // acquire
    __syncthreads();

    subtree<16, 4>(s2, out, iem, 16, 0, sm, tid, lp, q);
}

extern "C" void kernel_launch(void* const* d_in, const int* in_sizes, int n_in,
                              void* d_out, int out_size, void* d_ws, size_t ws_size,
                              hipStream_t stream) {
    const float* leaf  = (const float*)d_in[0];   // [8192,32]
    const float* iem   = (const float*)d_in[1];   // [8191,32]
    const float* trans = (const float*)d_in[2];   // [32,32,32]
    float* out = (float*)d_out;                   // [32]

    float* s1     = (float*)d_ws;                 // 256*32 f32   [0, 8192)
    float* s2     = s1 + 256 * 32;                // 16*32 f32    [8192, 8704)
    unsigned* cnt = (unsigned*)(s2 + 16 * 32);    // 1 u32 @ 8704, never reset
    float* wsE    = (float*)d_ws + 8720;          // 16384 f32 (64 KB bf16 E)

    (void)hipFuncSetAttribute((const void*)k1_kernel,
                              hipFuncAttributeMaxDynamicSharedMemorySize,
                              (int)SMEM_BYTES);
    (void)hipFuncSetAttribute((const void*)tail_kernel,
                              hipFuncAttributeMaxDynamicSharedMemorySize,
                              (int)SMEM_BYTES);

    k1_kernel<<<256, NT, SMEM_BYTES, stream>>>(leaf, s1, iem, trans, wsE);
    tail_kernel<<<16, NT, SMEM_BYTES, stream>>>(s1, s2, out, iem, wsE, cnt);
}

// Round 14
// 27.874 us; speedup vs baseline: 1.3395x; 1.3395x over previous
//
#include <hip/hip_runtime.h>
#include <math.h>

#define NLEAVES 8192
constexpr int NT = 512;             // 8 waves

typedef __fp16   h16x2 __attribute__((ext_vector_type(2)));   // cvt_pkrtz native
typedef _Float16 f16x2 __attribute__((ext_vector_type(2)));
typedef _Float16 f16x8 __attribute__((ext_vector_type(8)));
typedef float    f32x4 __attribute__((ext_vector_type(4)));

// ---- LDS layout (u32/f32 units) ----
// AF: E in MFMA A-frag layout: AF[(t*32+s)*64 + lane] = uint4 of 8 f16 =
//     E[lp = 16t + (lane&15)][l = s][r = (lane>>4)*8 .. +8]
// PF: P in B-frag layout: PF[s*64 + lane] = P[k=32s+(lane>>4)*8..+8][n=lane&15]
// PART: per-wave partial C tiles (8 x 256 f32, lane-major)
// AR: a-rows as dup f16 pairs, slot-stride 33 u32 (bank-spread)
// BB: b-rows as f16, slot-stride 80 B (16B-aligned, bank-spread)
constexpr int OFF_AF   = 0;                     // 16384 u32 (64 KB)
constexpr int OFF_PF   = 16384;                 // 8192 u32 (32 KB)
constexpr int OFF_PART = 24576;                 // 2048 f32
constexpr int OFF_AROW = 26624;                 // 32*33 u32
constexpr int OFF_BROW = 27680;                 // 32*20 u32 (80 B/slot)
constexpr int OFF_RM   = 28320;                 // 64 f32
constexpr int OFF_FLAG = 28384;
constexpr int SMEM_F32 = 28388;
constexpr size_t SMEM_BYTES = (size_t)SMEM_F32 * 4;   // ~111 KB -> 1 block/CU

__device__ __forceinline__ unsigned pkh(float a, float b) {
    h16x2 h = __builtin_amdgcn_cvt_pkrtz(a, b);
    return __builtin_bit_cast(unsigned, h);
}
__device__ __forceinline__ unsigned pkmul(unsigned a, unsigned b) {
    f16x2 x = __builtin_bit_cast(f16x2, a);
    f16x2 y = __builtin_bit_cast(f16x2, b);
    f16x2 r = x * y;                            // v_pk_mul_f16
    return __builtin_bit_cast(unsigned, r);
}

// Build exp(T) in f16 directly into A-fragment layout. Global reads coalesced
// (each 64B line consumed exactly by 2 lanes); LDS writes are lane-linear per
// wave (wave w, iter j writes exactly fragment block (t=j&1, s=w+8*(j>>1))).
__device__ __forceinline__ void build_AF(const float* __restrict__ trans,
                                         float* sm, int tid) {
    const float4* t4 = (const float4*)trans;    // t4[lp*256 + chunk*2 (+1)]
    uint4* AF = (uint4*)(sm + OFF_AF);
    const int lpl = tid & 15, hi = tid >> 4;    // hi = w*4 + og
    #pragma unroll
    for (int j = 0; j < 8; ++j) {
        const int lp    = lpl + 16 * (j & 1);
        const int chunk = hi + 32 * (j >> 1);   // = l*4 + oct, 0..127
        float4 va = t4[lp * 256 + chunk * 2];
        float4 vb = t4[lp * 256 + chunk * 2 + 1];
        uint4 u;
        u.x = pkh(__expf(va.x), __expf(va.y));
        u.y = pkh(__expf(va.z), __expf(va.w));
        u.z = pkh(__expf(vb.x), __expf(vb.y));
        u.w = pkh(__expf(vb.z), __expf(vb.w));
        AF[((j & 1) * 32 + (chunk >> 2)) * 64 + (((chunk & 3) << 4) | lpl)] = u;
    }
}

__device__ __forceinline__ void load_AF(const float* __restrict__ wsE,
                                        float* sm, int tid) {
    const uint4* src = (const uint4*)wsE;
    uint4* AF = (uint4*)(sm + OFF_AF);
    #pragma unroll
    for (int it = 0; it < 8; ++it)
        AF[tid + it * NT] = src[tid + it * NT];
}

// Reduce IN rows through LEVELS tree levels. Per level: build P (outer
// products, f16), GEMM OUT = E x P on MFMA (8 waves = 2 M-tiles x 4 K-quarters,
// K=1024), reduce partials + emissions + log in the epilogue.
// Row slot permutation slot(r) = (r&1)*16 + (r>>1) makes children (2n, 2n+1)
// land at slots (n, 16+n) -> conflict-free consecutive access in P-build.
template<int IN, int LEVELS>
__device__ __forceinline__
void subtree(const float* __restrict__ in, float* __restrict__ outp,
             const float* __restrict__ iem, int NTOT, int blk,
             float* sm, int tid) {
    const int lp = tid & 31, q = tid >> 5;
    uint4* AF = (uint4*)(sm + OFF_AF);
    uint4* PF = (uint4*)(sm + OFF_PF);
    float* PART = sm + OFF_PART;
    unsigned* AR = (unsigned*)(sm + OFF_AROW);
    char* BB = (char*)(sm + OFF_BROW);
    float* RM = sm + OFF_RM;

    // ---- prepass: rows -> exp(v - rowmax) in f16 (a: dup pairs, b: scalar) ----
    for (int rr = q; rr < IN; rr += 16) {
        float v = in[(blk * IN + rr) * 32 + lp];
        float gm = v;
        #pragma unroll
        for (int kk = 16; kk >= 1; kk >>= 1) gm = fmaxf(gm, __shfl_xor(gm, kk));
        const float e = __expf(v - gm);
        const int slot = (rr & 1) * 16 + (rr >> 1);
        AR[slot * 33 + lp] = pkh(e, e);
        *(_Float16*)(BB + slot * 80 + lp * 2) = (_Float16)e;
        if (lp == 0) RM[rr] = gm;
    }
    __syncthreads();

    #pragma unroll
    for (int k = 1; k <= LEVELS; ++k) {
        const int m = IN >> k;
        const float* rprev = RM + ((k & 1) ? 0 : 32);
        float*       rnext = RM + ((k & 1) ? 32 : 0);

        // ---- P build: P[:,n] = a_{2n} (x) b_{2n+1}, f16, B-frag layout ----
        {
            const int n = tid & 15, ocg = tid >> 4;
            #pragma unroll
            for (int j = 0; j < 4; ++j) {
                const int og = ocg + 32 * j;          // k-octet 0..127
                const int l = og >> 2, roct = og & 3;
                const unsigned aa = AR[n * 33 + l];   // slot(2n) = n (broadcast)
                const uint4 bv = *(const uint4*)(BB + (16 + n) * 80 + roct * 16);
                uint4 p;
                p.x = pkmul(aa, bv.x); p.y = pkmul(aa, bv.y);
                p.z = pkmul(aa, bv.z); p.w = pkmul(aa, bv.w);
                PF[l * 64 + ((roct << 4) | n)] = p;   // lane-linear write
            }
        }
        __syncthreads();

        // ---- MFMA: wave w = (t = w&1 M-tile) x (kq = w>>1 K-quarter) ----
        {
            const int w = tid >> 6, lane = tid & 63;
            const int t = w & 1, kq = w >> 1;
            f32x4 acc = {0.f, 0.f, 0.f, 0.f};
            #pragma unroll
            for (int s8 = 0; s8 < 8; ++s8) {
                const int s = kq * 8 + s8;
                f16x8 af = __builtin_bit_cast(f16x8, AF[(t * 32 + s) * 64 + lane]);
                f16x8 bf = __builtin_bit_cast(f16x8, PF[s * 64 + lane]);
                acc = __builtin_amdgcn_mfma_f32_16x16x32_f16(af, bf, acc, 0, 0, 0);
            }
            *(f32x4*)(PART + w * 256 + lane * 4) = acc;   // lane-linear
        }
        __syncthreads();

        // ---- epilogue: reduce 4 K-partials, + em + rmaxes + log ----
        {
            const int n = tid >> 5;                   // 0..15
            if (n < m) {
                const int t = lp >> 4, row = lp & 15;
                const int lane2 = ((row >> 2) << 4) | n, reg = row & 3;
                float sum = 0.f;
                #pragma unroll
                for (int kq = 0; kq < 4; ++kq)
                    sum += PART[(kq * 2 + t) * 256 + lane2 * 4 + reg];
                const float em = iem[(NLEAVES - 2 * (NTOT >> k) + blk * m + n) * 32 + lp];
                const float raw = em + rprev[2 * n] + rprev[2 * n + 1] + __logf(sum);
                if (k == LEVELS) {
                    outp[blk * 32 + lp] = raw;        // m==1, n==0
                } else {
                    float gm = raw;
                    #pragma unroll
                    for (int kk = 16; kk >= 1; kk >>= 1) gm = fmaxf(gm, __shfl_xor(gm, kk));
                    const float e = __expf(raw - gm);
                    const int slot = (n & 1) * 16 + (n >> 1);
                    AR[slot * 33 + lp] = pkh(e, e);
                    *(_Float16*)(BB + slot * 80 + lp * 2) = (_Float16)e;
                    if (lp == 0) rnext[n] = gm;
                }
            }
        }
        __syncthreads();
    }
}

// K1: 256 blocks, 32 leaves each -> s1[256 rows]. Block 0 spills the finished
// f16 A-fragment table (64 KB) to wsE so the tail skips the expf rebuild.
// Kernel boundary = the system-level flush for s1/wsE (R6/R7: intra-kernel
// 256-block handoff is racy; R9: grid.sync costs ~37us each).
__global__ __launch_bounds__(NT, 1)
void k1_kernel(const float* __restrict__ leaf, float* __restrict__ s1,
               const float* __restrict__ iem, const float* __restrict__ trans,
               float* __restrict__ wsE) {
    extern __shared__ __align__(16) float sm[];
    const int tid = threadIdx.x;
    build_AF(trans, sm, tid);
    __syncthreads();                              // AF complete
    if (blockIdx.x == 0) {
        const uint4* src = (const uint4*)(sm + OFF_AF);
        uint4* dst = (uint4*)wsE;
        #pragma unroll
        for (int it = 0; it < 8; ++it)
            dst[tid + it * NT] = src[tid + it * NT];
    }
    subtree<32, 5>(leaf, s1, iem, 8192, blockIdx.x, sm, tid);
}

// Tail: 16 blocks reduce s1(256 rows) -> s2(16 rows); the last arriver reduces
// s2(16) -> out. Persistent counter, never reset: among any 16 consecutive
// fetch_add returns exactly one satisfies (old&15)==15 (wrap-safe from the
// 0xAA poison) -> no memset node. Fence pattern is R5/R8/R11's verbatim.
__global__ __launch_bounds__(NT, 1)
void tail_kernel(const float* __restrict__ s1, float* __restrict__ s2,
                 float* __restrict__ out, const float* __restrict__ iem,
                 const float* __restrict__ wsE, unsigned* __restrict__ cnt) {
    extern __shared__ __align__(16) float sm[];
    const int tid = threadIdx.x;
    int* flag = (int*)(sm + OFF_FLAG);
    load_AF(wsE, sm, tid);
    subtree<16, 4>(s1, s2, iem, 256, blockIdx.x, sm, tid);

    if (tid == 0) {
        __threadfence();                          // release s2 row device-wide
        unsigned old = atomicAdd(cnt, 1u);
        *flag = ((old & 15u) == 15u) ? 1 : 0;
    }
    __syncthreads();
    if (!*flag) return;
    if (tid == 0) __threadfence();                // acquire
    __syncthreads();

    subtree<16, 4>(s2, out, iem, 16, 0, sm, tid);
}

extern "C" void kernel_launch(void* const* d_in, const int* in_sizes, int n_in,
                              void* d_out, int out_size, void* d_ws, size_t ws_size,
                              hipStream_t stream) {
    const float* leaf  = (const float*)d_in[0];   // [8192,32]
    const float* iem   = (const float*)d_in[1];   // [8191,32]
    const float* trans = (const float*)d_in[2];   // [32,32,32]
    float* out = (float*)d_out;                   // [32]

    float* s1     = (float*)d_ws;                 // 256*32 f32   [0, 8192)
    float* s2     = s1 + 256 * 32;                // 16*32 f32    [8192, 8704)
    unsigned* cnt = (unsigned*)(s2 + 16 * 32);    // 1 u32 @ 8704, never reset
    float* wsE    = (float*)d_ws + 8720;          // 16384 u32 (64 KB f16 AF)

    (void)hipFuncSetAttribute((const void*)k1_kernel,
                              hipFuncAttributeMaxDynamicSharedMemorySize,
                              (int)SMEM_BYTES);
    (void)hipFuncSetAttribute((const void*)tail_kernel,
                              hipFuncAttributeMaxDynamicSharedMemorySize,
                              (int)SMEM_BYTES);

    k1_kernel<<<256, NT, SMEM_BYTES, stream>>>(leaf, s1, iem, trans, wsE);
    tail_kernel<<<16, NT, SMEM_BYTES, stream>>>(s1, s2, out, iem, wsE, cnt);
}